// Round 2
// baseline (50.832 us; speedup 1.0000x reference)
//
#include <hip/hip_runtime.h>

// Elementwise: y = x*w + b (w,b broadcast over batch); out = y if 0 < y <= 1 else 0.
// x: [8192, 4096] f32, w: [4096] f32, b: [4096] f32, out: [8192, 4096] f32.
// Memory-bound: ~268 MB HBM traffic -> floor ~38 us at the ~7 TB/s demonstrated ceiling.
//
// Key points:
//  - grid-stride (2048 blocks x 256 thr = 524288 lanes) in float4 units is a
//    multiple of 1024 (= 4096 floats / 4), so each thread's w/b column is
//    LOOP-INVARIANT -> hoist the w/b loads out of the loop (compiler can't
//    prove this with a runtime stride).
//  - nontemporal load/store for the streaming x/out traffic (no reuse).

typedef float f32x4 __attribute__((ext_vector_type(4)));

__global__ void __launch_bounds__(256)
capped_relu_kernel(const f32x4* __restrict__ x4,
                   const float* __restrict__ w,
                   const float* __restrict__ b,
                   f32x4* __restrict__ out4,
                   long n4) {
    const long stride = (long)gridDim.x * blockDim.x;   // multiple of 1024 by construction
    long i = (long)blockIdx.x * blockDim.x + threadIdx.x;
    if (i >= n4) return;

    // Column of this thread's float4 — invariant across grid-stride iterations
    // because stride*4 % 4096 == 0.
    const int c = (int)((i << 2) & 4095);
    const f32x4 wv = *reinterpret_cast<const f32x4*>(&w[c]);
    const f32x4 bv = *reinterpret_cast<const f32x4*>(&b[c]);

    for (; i < n4; i += stride) {
        f32x4 v = __builtin_nontemporal_load(&x4[i]);
        f32x4 y = v * wv + bv;
        f32x4 r;
        r.x = (y.x > 0.0f && y.x <= 1.0f) ? y.x : 0.0f;
        r.y = (y.y > 0.0f && y.y <= 1.0f) ? y.y : 0.0f;
        r.z = (y.z > 0.0f && y.z <= 1.0f) ? y.z : 0.0f;
        r.w = (y.w > 0.0f && y.w <= 1.0f) ? y.w : 0.0f;
        __builtin_nontemporal_store(r, &out4[i]);
    }
}

extern "C" void kernel_launch(void* const* d_in, const int* in_sizes, int n_in,
                              void* d_out, int out_size, void* d_ws, size_t ws_size,
                              hipStream_t stream) {
    const float* x = (const float*)d_in[0];
    const float* w = (const float*)d_in[1];
    const float* b = (const float*)d_in[2];
    float* out = (float*)d_out;

    const long n  = (long)out_size;        // 8192 * 4096
    const long n4 = n >> 2;                // float4 count (n is a multiple of 4)

    const int block = 256;
    long blocks_needed = (n4 + block - 1) / block;
    int grid = (int)((blocks_needed < 2048) ? blocks_needed : 2048);

    capped_relu_kernel<<<grid, block, 0, stream>>>(
        (const f32x4*)x, w, b, (f32x4*)out, n4);
}

// Round 3
// 45.484 us; speedup vs baseline: 1.1176x; 1.1176x over previous
//
#include <hip/hip_runtime.h>

// Elementwise: y = x*w + b (w,b broadcast over batch); out = y if 0 < y <= 1 else 0.
// x: [8192, 4096] f32, w: [4096] f32, b: [4096] f32, out: [8192, 4096] f32.
// Memory-bound: ~268 MB HBM traffic; measured float4-copy ceiling 6.29 TB/s -> ~42.7 us floor.
//
// Round-2 lesson: __builtin_nontemporal_* REGRESSED (45.4 -> 50.8 us) — nt
// bypasses the L2 write-combine path. Plain loads/stores here.
//
// Key points:
//  - grid-stride (2048 blocks x 256 thr = 524288 lanes) in float4 units is a
//    multiple of 1024 (= 4096 floats / 4), so each thread's w/b column is
//    LOOP-INVARIANT -> w/b loads hoisted out of the loop.
//  - n4 (8388608) = 16 x lane count, so exactly 8 unrolled-x2 iterations, no tail.
//  - 2x unroll: two independent load/store pairs in flight per iteration (MLP).

typedef float f32x4 __attribute__((ext_vector_type(4)));

__device__ __forceinline__ f32x4 capped(f32x4 y) {
    f32x4 r;
    r.x = (y.x > 0.0f && y.x <= 1.0f) ? y.x : 0.0f;
    r.y = (y.y > 0.0f && y.y <= 1.0f) ? y.y : 0.0f;
    r.z = (y.z > 0.0f && y.z <= 1.0f) ? y.z : 0.0f;
    r.w = (y.w > 0.0f && y.w <= 1.0f) ? y.w : 0.0f;
    return r;
}

__global__ void __launch_bounds__(256)
capped_relu_kernel(const f32x4* __restrict__ x4,
                   const float* __restrict__ w,
                   const float* __restrict__ b,
                   f32x4* __restrict__ out4,
                   long n4) {
    const long stride = (long)gridDim.x * blockDim.x;   // multiple of 1024 by construction
    long i = (long)blockIdx.x * blockDim.x + threadIdx.x;
    if (i >= n4) return;

    // Column of this thread's float4 — invariant across grid-stride iterations
    // because stride*4 % 4096 == 0.
    const int c = (int)((i << 2) & 4095);
    const f32x4 wv = *reinterpret_cast<const f32x4*>(&w[c]);
    const f32x4 bv = *reinterpret_cast<const f32x4*>(&b[c]);

    // Main loop: 2 independent load/store pairs per iteration.
    for (; i + stride < n4; i += 2 * stride) {
        f32x4 v0 = x4[i];
        f32x4 v1 = x4[i + stride];
        f32x4 r0 = capped(v0 * wv + bv);
        f32x4 r1 = capped(v1 * wv + bv);
        out4[i] = r0;
        out4[i + stride] = r1;
    }
    if (i < n4) {
        out4[i] = capped(x4[i] * wv + bv);
    }
}

extern "C" void kernel_launch(void* const* d_in, const int* in_sizes, int n_in,
                              void* d_out, int out_size, void* d_ws, size_t ws_size,
                              hipStream_t stream) {
    const float* x = (const float*)d_in[0];
    const float* w = (const float*)d_in[1];
    const float* b = (const float*)d_in[2];
    float* out = (float*)d_out;

    const long n  = (long)out_size;        // 8192 * 4096
    const long n4 = n >> 2;                // float4 count (n is a multiple of 4)

    const int block = 256;
    long blocks_needed = (n4 + block - 1) / block;
    int grid = (int)((blocks_needed < 2048) ? blocks_needed : 2048);

    capped_relu_kernel<<<grid, block, 0, stream>>>(
        (const f32x4*)x, w, b, (f32x4*)out, n4);
}